// Round 2
// baseline (460.649 us; speedup 1.0000x reference)
//
#include <hip/hip_runtime.h>
#include <hip/hip_bf16.h>
#include <hip/hip_cooperative_groups.h>

namespace cg = cooperative_groups;

#define N_NODES 50000
#define N_EDGES 800000
#define EMB 64
#define HID 64
#define N_CLASSES 10
#define N_GRAPHS 512

#define BKT_SHIFT 6
#define BKT_NODES 64
#define NB_BKT ((N_NODES + BKT_NODES - 1) / BKT_NODES)   // 782
#define BKT_CAP 1408     // mean 1024 + 12 sigma
#define CNT_STRIDE 16    // one counter per 64B line: kills cross-XCD false sharing
#define EB_CHUNK 4096
#define EB_BLOCKS ((N_EDGES + EB_CHUNK - 1) / EB_CHUNK)  // 196
#define XFORM_BLOCKS ((N_NODES + 63) / 64)               // 782
#define XPAD 68

// bf16 row accumulate: 8 bf16 dims (uint4) into fp32[8]
#define ACC8(vv, A)                                                            \
    do {                                                                       \
        A[0] += __uint_as_float((vv).x << 16);                                 \
        A[1] += __uint_as_float((vv).x & 0xFFFF0000u);                         \
        A[2] += __uint_as_float((vv).y << 16);                                 \
        A[3] += __uint_as_float((vv).y & 0xFFFF0000u);                         \
        A[4] += __uint_as_float((vv).z << 16);                                 \
        A[5] += __uint_as_float((vv).z & 0xFFFF0000u);                         \
        A[6] += __uint_as_float((vv).w << 16);                                 \
        A[7] += __uint_as_float((vv).w & 0xFFFF0000u);                         \
    } while (0)

// Build this bucket's CSR in LDS from its ebuf region. All 256 threads.
__device__ __forceinline__ void build_local_csr(
    int bucket, const int* __restrict__ cnt, const int* __restrict__ ebuf,
    unsigned short* lcsr, int* nhist, int* sval, int* sexcl, int* ncur) {
    int tid = threadIdx.x;
    int bs = bucket * BKT_CAP;
    int ne = min(cnt[bucket * CNT_STRIDE], BKT_CAP);   // defensive clamp
    if (tid < BKT_NODES) { nhist[tid] = 0; ncur[tid] = 0; }
    __syncthreads();
    for (int i = tid; i < ne; i += 256)
        atomicAdd(&nhist[ebuf[bs + i] >> 16], 1);
    __syncthreads();
    if (tid < 64) {            // wave 0: inclusive scan via shfl_up
        int v = nhist[tid];
        int s = v;
#pragma unroll
        for (int off = 1; off < 64; off <<= 1) {
            int u = __shfl_up(s, off, 64);
            if (tid >= off) s += u;
        }
        sval[tid] = v;
        sexcl[tid] = s - v;
    }
    __syncthreads();
    for (int i = tid; i < ne; i += 256) {
        int p = ebuf[bs + i];
        int l = p >> 16;
        int r = atomicAdd(&ncur[l], 1);
        lcsr[sexcl[l] + r] = (unsigned short)(p & 0xFFFF);
    }
    __syncthreads();
}

// Dual-node mean aggregation: both nodes' chunks in flight (16 outstanding
// 16B gathers) to double memory-level parallelism vs sequential nodes.
__device__ __forceinline__ void agg2(
    int sA, int dA, int sB, int dB, int sl,
    const unsigned short* lcsr, const __hip_bfloat16* __restrict__ Pb,
    float oA[8], float oB[8]) {
    float a0[8], a1[8], b0[8], b1[8];
#pragma unroll
    for (int j = 0; j < 8; j++) { a0[j] = 0.f; a1[j] = 0.f; b0[j] = 0.f; b1[j] = 0.f; }
    int eA = sA + dA, eB = sB + dB;
    int pA = sA, pB = sB;
    while ((pA + 8 <= eA) && (pB + 8 <= eB)) {
        uint4 vA[8], vB[8];
#pragma unroll
        for (int j = 0; j < 8; j++)
            vA[j] = ((const uint4*)(Pb + (size_t)lcsr[pA + j] * 64))[sl];
#pragma unroll
        for (int j = 0; j < 8; j++)
            vB[j] = ((const uint4*)(Pb + (size_t)lcsr[pB + j] * 64))[sl];
#pragma unroll
        for (int j = 0; j < 8; j++) ACC8(vA[j], ((j & 1) ? a1 : a0));
#pragma unroll
        for (int j = 0; j < 8; j++) ACC8(vB[j], ((j & 1) ? b1 : b0));
        pA += 8; pB += 8;
    }
    while (pA + 8 <= eA) {
        uint4 v[8];
#pragma unroll
        for (int j = 0; j < 8; j++)
            v[j] = ((const uint4*)(Pb + (size_t)lcsr[pA + j] * 64))[sl];
#pragma unroll
        for (int j = 0; j < 8; j++) ACC8(v[j], ((j & 1) ? a1 : a0));
        pA += 8;
    }
    while (pB + 8 <= eB) {
        uint4 v[8];
#pragma unroll
        for (int j = 0; j < 8; j++)
            v[j] = ((const uint4*)(Pb + (size_t)lcsr[pB + j] * 64))[sl];
#pragma unroll
        for (int j = 0; j < 8; j++) ACC8(v[j], ((j & 1) ? b1 : b0));
        pB += 8;
    }
    for (; pA < eA; ++pA) {
        uint4 v = ((const uint4*)(Pb + (size_t)lcsr[pA] * 64))[sl];
        ACC8(v, a0);
    }
    for (; pB < eB; ++pB) {
        uint4 v = ((const uint4*)(Pb + (size_t)lcsr[pB] * 64))[sl];
        ACC8(v, b0);
    }
    float invA = (dA > 0) ? 1.0f / (float)dA : 0.0f;
    float invB = (dB > 0) ? 1.0f / (float)dB : 0.0f;
#pragma unroll
    for (int j = 0; j < 8; j++) {
        oA[j] = (a0[j] + a1[j]) * invA;
        oB[j] = (b0[j] + b1[j]) * invB;
    }
}

// m += Q (from H), relu, stage 8 dims into dst[sl*8..sl*8+7]
__device__ __forceinline__ void finish_row(int node, int sl,
                                           const float* __restrict__ H,
                                           float m[8], float* dst) {
    if (node < N_NODES) {
        size_t off = (size_t)node * 64 + sl * 8;
        float4 q0 = *(const float4*)&H[off];
        float4 q1 = *(const float4*)&H[off + 4];
        m[0] = fmaxf(m[0] + q0.x, 0.f);
        m[1] = fmaxf(m[1] + q0.y, 0.f);
        m[2] = fmaxf(m[2] + q0.z, 0.f);
        m[3] = fmaxf(m[3] + q0.w, 0.f);
        m[4] = fmaxf(m[4] + q1.x, 0.f);
        m[5] = fmaxf(m[5] + q1.y, 0.f);
        m[6] = fmaxf(m[6] + q1.z, 0.f);
        m[7] = fmaxf(m[7] + q1.w, 0.f);
    } else {
#pragma unroll
        for (int j = 0; j < 8; j++) m[j] = 0.f;
    }
    *(float4*)&dst[sl * 8] = make_float4(m[0], m[1], m[2], m[3]);
    *(float4*)&dst[sl * 8 + 4] = make_float4(m[4], m[5], m[6], m[7]);
}

// Two 64x64x64 fp32 GEMM passes from staged sX. Precondition: sW holds Wl,
// sX holds 64 input rows (XPAD stride), all threads synced.
// Pass 1: Pb = sX @ Wl (bf16, no bias). Pass 2: Qout = sX @ Wr + bl (f32).
__device__ __forceinline__ void two_gemm_from_sX(
    int tile, int t, float* sW, const float* sX,
    const float* __restrict__ Wr, const float* __restrict__ bl,
    __hip_bfloat16* __restrict__ Pb, float* __restrict__ Qout) {
    int dg = t & 15, ng = t >> 4;
    float acc[4][4];
#pragma unroll
    for (int i = 0; i < 4; i++)
#pragma unroll
        for (int j = 0; j < 4; j++) acc[i][j] = 0.f;
#pragma unroll 4
    for (int k = 0; k < 64; k++) {
        float4 w = *(const float4*)&sW[k * 64 + dg * 4];
#pragma unroll
        for (int i = 0; i < 4; i++) {
            float xv = sX[(ng + i * 16) * XPAD + k];
            acc[i][0] = fmaf(xv, w.x, acc[i][0]);
            acc[i][1] = fmaf(xv, w.y, acc[i][1]);
            acc[i][2] = fmaf(xv, w.z, acc[i][2]);
            acc[i][3] = fmaf(xv, w.w, acc[i][3]);
        }
    }
#pragma unroll
    for (int i = 0; i < 4; i++) {
        int node = tile + ng + i * 16;
        if (node < N_NODES) {
            union { ushort4 u; __hip_bfloat16 h[4]; } pk;
            pk.h[0] = __float2bfloat16(acc[i][0]);
            pk.h[1] = __float2bfloat16(acc[i][1]);
            pk.h[2] = __float2bfloat16(acc[i][2]);
            pk.h[3] = __float2bfloat16(acc[i][3]);
            *(ushort4*)&Pb[(size_t)node * 64 + dg * 4] = pk.u;
        }
    }
    __syncthreads();
    for (int i = t; i < 64 * 16; i += 256)
        ((float4*)sW)[i] = ((const float4*)Wr)[i];
    __syncthreads();
#pragma unroll
    for (int i = 0; i < 4; i++)
#pragma unroll
        for (int j = 0; j < 4; j++) acc[i][j] = 0.f;
#pragma unroll 4
    for (int k = 0; k < 64; k++) {
        float4 w = *(const float4*)&sW[k * 64 + dg * 4];
#pragma unroll
        for (int i = 0; i < 4; i++) {
            float xv = sX[(ng + i * 16) * XPAD + k];
            acc[i][0] = fmaf(xv, w.x, acc[i][0]);
            acc[i][1] = fmaf(xv, w.y, acc[i][1]);
            acc[i][2] = fmaf(xv, w.z, acc[i][2]);
            acc[i][3] = fmaf(xv, w.w, acc[i][3]);
        }
    }
    float4 blv = *(const float4*)&bl[dg * 4];
#pragma unroll
    for (int i = 0; i < 4; i++) {
        int node = tile + ng + i * 16;
        if (node < N_NODES)
            *(float4*)&Qout[(size_t)node * 64 + dg * 4] =
                make_float4(acc[i][0] + blv.x, acc[i][1] + blv.y,
                            acc[i][2] + blv.z, acc[i][3] + blv.w);
    }
}

// ---- phase-A unit: bucket multi-split for one edge chunk ----
__device__ __forceinline__ void unit_bsplit(
    int u, int t, const int* __restrict__ esrc, const int* __restrict__ edst,
    int* __restrict__ cnt, int* __restrict__ ebuf, float* sW, float* sX) {
    int* h = (int*)sW;                 // NB_BKT
    int* bbase = h + NB_BKT;           // NB_BKT
    int* cur = (int*)sX;               // NB_BKT
    for (int i = t; i < NB_BKT; i += 256) { h[i] = 0; cur[i] = 0; }
    __syncthreads();
    int base = u * EB_CHUNK;
    int end = min(base + EB_CHUNK, N_EDGES);
    for (int i = base + t; i < end; i += 256)
        atomicAdd(&h[edst[i] >> BKT_SHIFT], 1);
    __syncthreads();
    for (int i = t; i < NB_BKT; i += 256)
        if (h[i]) bbase[i] = i * BKT_CAP + atomicAdd(&cnt[i * CNT_STRIDE], h[i]);
    __syncthreads();
    for (int i = base + t; i < end; i += 256) {
        int d = edst[i], s = esrc[i];
        int b = d >> BKT_SHIFT;
        int r = atomicAdd(&cur[b], 1);
        int slot = bbase[b] + r;
        if (slot < (b + 1) * BKT_CAP)          // defensive clamp
            ebuf[slot] = ((d & (BKT_NODES - 1)) << 16) | s;
    }
}

// ---- phase-A unit: layer-0 transform for one 64-node tile ----
__device__ __forceinline__ void unit_xform0(
    int tileIdx, int t, const int* __restrict__ ids, const float* __restrict__ emb,
    const float* __restrict__ Wl, const float* __restrict__ bl,
    const float* __restrict__ Wr, __hip_bfloat16* __restrict__ Pb,
    float* __restrict__ Qout, float* sW, float* sX) {
    int tile = tileIdx * 64;
    for (int i = t; i < 64 * 16; i += 256)
        ((float4*)sW)[i] = ((const float4*)Wl)[i];
    for (int i = t; i < 64 * 16; i += 256) {
        int r = i >> 4, c = i & 15;
        int node = tile + r;
        float4 v = make_float4(0.f, 0.f, 0.f, 0.f);
        if (node < N_NODES)
            v = ((const float4*)(emb + (size_t)ids[node] * 64))[c];
        *(float4*)&sX[r * XPAD + c * 4] = v;
    }
    __syncthreads();
    two_gemm_from_sX(tile, t, sW, sX, Wr, bl, Pb, Qout);
}

// ---- phase-B unit: layer-0 aggregate + layer-1 transform for one bucket ----
__device__ __forceinline__ void unit_fused1(
    int u, int t, const int* __restrict__ cnt, const int* __restrict__ ebuf,
    const __hip_bfloat16* __restrict__ Pb0, const float* __restrict__ Wl,
    const float* __restrict__ bl, const float* __restrict__ Wr,
    __hip_bfloat16* __restrict__ Pb1, float* __restrict__ H,
    float* sW, float* sX, unsigned short* lcsr,
    int* nhist, int* sval, int* sexcl, int* ncur) {
    int tile = u * 64;
    for (int i = t; i < 64 * 16; i += 256)
        ((float4*)sW)[i] = ((const float4*)Wl)[i];
    build_local_csr(u, cnt, ebuf, lcsr, nhist, sval, sexcl, ncur);
    int grp = t >> 3, sl = t & 7;
    int ln0 = grp * 2, ln1 = ln0 + 1;
    float mA[8], mB[8];
    agg2(sexcl[ln0], sval[ln0], sexcl[ln1], sval[ln1], sl, lcsr, Pb0, mA, mB);
    finish_row(tile + ln0, sl, H, mA, &sX[ln0 * XPAD]);
    finish_row(tile + ln1, sl, H, mB, &sX[ln1 * XPAD]);
    __syncthreads();
    two_gemm_from_sX(tile, t, sW, sX, Wr, bl, Pb1, H);
}

// ---- phase-C unit: layer-1 aggregate + pooling for one bucket ----
__device__ __forceinline__ void unit_agg2pool(
    int u, int t, const int* __restrict__ cnt, const int* __restrict__ ebuf,
    const __hip_bfloat16* __restrict__ Pb, const float* __restrict__ H,
    const int* __restrict__ batch, float* __restrict__ psum,
    float* sPool, unsigned short* lcsr,
    int* nhist, int* sval, int* sexcl, int* ncur, int* sLg) {
    int nb = u * 64;
    int gmin = batch[nb];
    if (t < 64) {
        int node = nb + t;
        sLg[t] = batch[node < N_NODES ? node : (N_NODES - 1)] - gmin;
    }
    build_local_csr(u, cnt, ebuf, lcsr, nhist, sval, sexcl, ncur);
    int grp = t >> 3, sl = t & 7;
    int ln0 = grp * 2, ln1 = ln0 + 1;
    float mA[8], mB[8];
    agg2(sexcl[ln0], sval[ln0], sexcl[ln1], sval[ln1], sl, lcsr, Pb, mA, mB);
    finish_row(nb + ln0, sl, H, mA, &sPool[ln0 * 64]);
    finish_row(nb + ln1, sl, H, mB, &sPool[ln1 * 64]);
    __syncthreads();
    // segmented per-dim sum over this bucket's 64 rows (batch sorted -> lg
    // non-decreasing). Each thread owns one dim x one 16-node quarter.
    int d = t & 63, q = t >> 6;
    int n0 = q * 16;
    float run = 0.f;
    int cur = sLg[n0];
    for (int n = n0; n < n0 + 16; n++) {
        int lg = sLg[n];
        if (lg != cur) {
            if (run != 0.f)
                atomicAdd(&psum[(size_t)(gmin + cur) * 64 + d], run);
            run = 0.f;
            cur = lg;
        }
        run += sPool[n * 64 + d];
    }
    if (run != 0.f)
        atomicAdd(&psum[(size_t)(gmin + cur) * 64 + d], run);
}

__device__ __forceinline__ int lower_bound_batch(const int* __restrict__ batch, int val) {
    int lo = 0, hi = N_NODES;
    while (lo < hi) {
        int mid = (lo + hi) >> 1;
        if (batch[mid] < val) lo = mid + 1; else hi = mid;
    }
    return lo;
}

// ================= cooperative mega-kernel =================
__global__ __launch_bounds__(256, 4) void k_all(
    const int* __restrict__ esrc, const int* __restrict__ edst,
    int* __restrict__ cnt, int* __restrict__ ebuf,
    const int* __restrict__ ids, const float* __restrict__ emb,
    const float* __restrict__ Wl0, const float* __restrict__ bl0,
    const float* __restrict__ Wr0,
    __hip_bfloat16* __restrict__ Pb0, float* __restrict__ H,
    const float* __restrict__ Wl1, const float* __restrict__ bl1,
    const float* __restrict__ Wr1, __hip_bfloat16* __restrict__ Pb1,
    const int* __restrict__ batch, float* __restrict__ psum,
    int* __restrict__ wq,
    const float* __restrict__ Wout, const float* __restrict__ bout,
    float* __restrict__ out) {
    cg::grid_group grid = cg::this_grid();
    __shared__ float sW[64 * 64];          // 16 KB; phase C: pool staging
    __shared__ float sX[64 * XPAD];        // 17.4 KB
    __shared__ unsigned short lcsr[BKT_CAP];
    __shared__ int nhist[BKT_NODES], sval[BKT_NODES], sexcl[BKT_NODES], ncur[BKT_NODES];
    __shared__ int sLg[BKT_NODES];
    __shared__ int sU;
    int t = threadIdx.x;

    // ---- phase 0: zero cnt + psum + work queues (replaces hipMemsetAsync) ----
    {
        int4* zb = (int4*)cnt;   // cnt..psum..wq contiguous, 16B aligned
        const int zi4 = (NB_BKT * CNT_STRIDE + N_GRAPHS * 64 + 8) >> 2;
        for (int i = blockIdx.x * 256 + t; i < zi4; i += gridDim.x * 256)
            zb[i] = make_int4(0, 0, 0, 0);
    }
    grid.sync();

    // ---- phase A: bsplit chunks + layer-0 transform tiles (dynamic queue) ----
    const int NU_A = EB_BLOCKS + XFORM_BLOCKS;
    for (;;) {
        __syncthreads();
        if (t == 0) sU = atomicAdd(&wq[0], 1);
        __syncthreads();
        int u = sU;
        if (u >= NU_A) break;
        if (u < EB_BLOCKS)
            unit_bsplit(u, t, esrc, edst, cnt, ebuf, sW, sX);
        else
            unit_xform0(u - EB_BLOCKS, t, ids, emb, Wl0, bl0, Wr0, Pb0, H, sW, sX);
    }
    grid.sync();

    // ---- phase B: layer-0 aggregate + layer-1 transform ----
    for (;;) {
        __syncthreads();
        if (t == 0) sU = atomicAdd(&wq[1], 1);
        __syncthreads();
        int u = sU;
        if (u >= NB_BKT) break;
        unit_fused1(u, t, cnt, ebuf, Pb0, Wl1, bl1, Wr1, Pb1, H,
                    sW, sX, lcsr, nhist, sval, sexcl, ncur);
    }
    grid.sync();

    // ---- phase C: layer-1 aggregate + pooling ----
    for (;;) {
        __syncthreads();
        if (t == 0) sU = atomicAdd(&wq[2], 1);
        __syncthreads();
        int u = sU;
        if (u >= NB_BKT) break;
        unit_agg2pool(u, t, cnt, ebuf, Pb1, H, batch, psum,
                      sW, lcsr, nhist, sval, sexcl, ncur, sLg);
    }
    grid.sync();

    // ---- phase D: output projection ----
    int w = t >> 6, lane = t & 63;
    for (int g = blockIdx.x * 4 + w; g < N_GRAPHS; g += gridDim.x * 4) {
        int s0 = lower_bound_batch(batch, g);
        int s1 = lower_bound_batch(batch, g + 1);
        int cntg = s1 - s0;
        float inv = (cntg > 0) ? 1.0f / (float)cntg : 0.0f;
        float pooled = psum[(size_t)g * 64 + lane] * inv;
#pragma unroll
        for (int c = 0; c < N_CLASSES; c++) {
            float v = pooled * Wout[lane * N_CLASSES + c];
#pragma unroll
            for (int off = 32; off > 0; off >>= 1) v += __shfl_down(v, off, 64);
            if (lane == 0) out[(size_t)g * N_CLASSES + c] = v + bout[c];
        }
    }
}

// ================= legacy fallback kernels (proven path) =================
__global__ __launch_bounds__(256) void k_combo(
    const int* __restrict__ esrc, const int* __restrict__ edst,
    int* __restrict__ cnt, int* __restrict__ ebuf,
    const int* __restrict__ ids, const float* __restrict__ emb,
    const float* __restrict__ Wl, const float* __restrict__ bl,
    const float* __restrict__ Wr,
    __hip_bfloat16* __restrict__ Pb, float* __restrict__ Qout) {
    __shared__ float sW[64 * 64];
    __shared__ float sX[64 * XPAD];
    int t = threadIdx.x;
    if (blockIdx.x < EB_BLOCKS) {
        unit_bsplit(blockIdx.x, t, esrc, edst, cnt, ebuf, sW, sX);
        return;
    }
    unit_xform0(blockIdx.x - EB_BLOCKS, t, ids, emb, Wl, bl, Wr, Pb, Qout, sW, sX);
}

__global__ __launch_bounds__(256, 4) void k_fused1(
    const int* __restrict__ cnt, const int* __restrict__ ebuf,
    const __hip_bfloat16* __restrict__ Pb0, const float* __restrict__ Wl,
    const float* __restrict__ bl, const float* __restrict__ Wr,
    __hip_bfloat16* __restrict__ Pb1, float* __restrict__ H) {
    __shared__ float sW[64 * 64];
    __shared__ float sX[64 * XPAD];
    __shared__ unsigned short lcsr[BKT_CAP];
    __shared__ int nhist[BKT_NODES], sval[BKT_NODES], sexcl[BKT_NODES], ncur[BKT_NODES];
    unit_fused1(blockIdx.x, threadIdx.x, cnt, ebuf, Pb0, Wl, bl, Wr, Pb1, H,
                sW, sX, lcsr, nhist, sval, sexcl, ncur);
}

__global__ __launch_bounds__(256, 4) void k_agg2_pool(
    const int* __restrict__ cnt, const int* __restrict__ ebuf,
    const __hip_bfloat16* __restrict__ Pb, const float* __restrict__ H,
    const int* __restrict__ batch, float* __restrict__ psum) {
    __shared__ float sPool[64 * 64];
    __shared__ unsigned short lcsr[BKT_CAP];
    __shared__ int nhist[BKT_NODES], sval[BKT_NODES], sexcl[BKT_NODES], ncur[BKT_NODES];
    __shared__ int sLg[64];
    unit_agg2pool(blockIdx.x, threadIdx.x, cnt, ebuf, Pb, H, batch, psum,
                  sPool, lcsr, nhist, sval, sexcl, ncur, sLg);
}

__global__ __launch_bounds__(256) void k_out(
    const int* __restrict__ batch, const float* __restrict__ psum,
    const float* __restrict__ Wout, const float* __restrict__ bout,
    float* __restrict__ out) {
    int w = threadIdx.x >> 6, lane = threadIdx.x & 63;
    int g = blockIdx.x * 4 + w;
    if (g >= N_GRAPHS) return;
    int s0 = lower_bound_batch(batch, g);
    int s1 = lower_bound_batch(batch, g + 1);
    int cntg = s1 - s0;
    float inv = (cntg > 0) ? 1.0f / (float)cntg : 0.0f;
    float pooled = psum[(size_t)g * 64 + lane] * inv;
#pragma unroll
    for (int c = 0; c < N_CLASSES; c++) {
        float v = pooled * Wout[lane * N_CLASSES + c];
#pragma unroll
        for (int off = 32; off > 0; off >>= 1) v += __shfl_down(v, off, 64);
        if (lane == 0) out[(size_t)g * N_CLASSES + c] = v + bout[c];
    }
}

// ---------------- launch ----------------

extern "C" void kernel_launch(void* const* d_in, const int* in_sizes, int n_in,
                              void* d_out, int out_size, void* d_ws, size_t ws_size,
                              hipStream_t stream) {
    const int*   node_ids = (const int*)d_in[0];
    const int*   edge_idx = (const int*)d_in[1];   // [2, E] row-major
    const int*   batch    = (const int*)d_in[2];
    const float* emb      = (const float*)d_in[3];
    const float* Wl0      = (const float*)d_in[4];
    const float* bl0      = (const float*)d_in[5];
    const float* Wr0      = (const float*)d_in[6];
    const float* Wl1      = (const float*)d_in[7];
    const float* bl1      = (const float*)d_in[8];
    const float* Wr1      = (const float*)d_in[9];
    const float* Wout     = (const float*)d_in[10];
    const float* bout     = (const float*)d_in[11];
    float* out = (float*)d_out;

    const int* esrc = edge_idx;
    const int* edst = edge_idx + N_EDGES;

    // workspace layout
    __hip_bfloat16* Pb0 = (__hip_bfloat16*)d_ws;              // N*64 bf16
    __hip_bfloat16* Pb1 = Pb0 + (size_t)N_NODES * 64;         // N*64 bf16
    float* H = (float*)(Pb1 + (size_t)N_NODES * 64);          // N*64 f32
    int* ebuf = (int*)(H + (size_t)N_NODES * 64);             // NB*CAP ints
    int* cnt = ebuf + (size_t)NB_BKT * BKT_CAP;               // NB*CNT_STRIDE ints
    float* psum = (float*)(cnt + (size_t)NB_BKT * CNT_STRIDE); // G*64 floats
    int* wq = (int*)(psum + (size_t)N_GRAPHS * 64);           // 8 ints (queues)

    const int BLK = 256;

    // grid = co-resident capacity (cooperative requirement), capped at work
    static int s_grid = -1;
    if (s_grid < 0) {
        int nb = 0;
        if (hipOccupancyMaxActiveBlocksPerMultiprocessor(&nb, k_all, BLK, 0)
                != hipSuccess || nb < 1)
            nb = 0;
        s_grid = nb * 256;                       // 256 CUs on MI355X
        if (s_grid > EB_BLOCKS + XFORM_BLOCKS) s_grid = EB_BLOCKS + XFORM_BLOCKS;
    }

    bool ok = false;
    if (s_grid >= 256) {
        void* args[] = {(void*)&esrc, (void*)&edst, (void*)&cnt, (void*)&ebuf,
                        (void*)&node_ids, (void*)&emb, (void*)&Wl0, (void*)&bl0,
                        (void*)&Wr0, (void*)&Pb0, (void*)&H, (void*)&Wl1,
                        (void*)&bl1, (void*)&Wr1, (void*)&Pb1, (void*)&batch,
                        (void*)&psum, (void*)&wq, (void*)&Wout, (void*)&bout,
                        (void*)&out};
        ok = (hipLaunchCooperativeKernel(k_all, dim3(s_grid), dim3(BLK),
                                         args, 0, stream) == hipSuccess);
    }
    if (!ok) {
        // fallback: proven 5-dispatch path
        hipMemsetAsync(cnt, 0, (NB_BKT * CNT_STRIDE + N_GRAPHS * 64) * sizeof(int),
                       stream);
        k_combo<<<EB_BLOCKS + XFORM_BLOCKS, BLK, 0, stream>>>(
            esrc, edst, cnt, ebuf, node_ids, emb, Wl0, bl0, Wr0, Pb0, H);
        k_fused1<<<XFORM_BLOCKS, BLK, 0, stream>>>(cnt, ebuf, Pb0, Wl1, bl1, Wr1,
                                                   Pb1, H);
        k_agg2_pool<<<NB_BKT, BLK, 0, stream>>>(cnt, ebuf, Pb1, H, batch, psum);
        k_out<<<(N_GRAPHS + 3) / 4, BLK, 0, stream>>>(batch, psum, Wout, bout, out);
    }
}

// Round 4
// 188.329 us; speedup vs baseline: 2.4460x; 2.4460x over previous
//
#include <hip/hip_runtime.h>
#include <hip/hip_bf16.h>

#define N_NODES 50000
#define N_EDGES 800000
#define EMB 64
#define HID 64
#define N_CLASSES 10
#define N_GRAPHS 512

#define BKT_SHIFT 6
#define BKT_NODES 64
#define NB_BKT ((N_NODES + BKT_NODES - 1) / BKT_NODES)   // 782
#define BKT_CAP 1408     // mean 1024 + 12 sigma
#define CNT_STRIDE 16    // one counter per 64B line: kills cross-XCD false sharing
#define EB_CHUNK 4096
#define EB_PER_THR (EB_CHUNK / 256)                      // 16
#define EB_BLOCKS ((N_EDGES + EB_CHUNK - 1) / EB_CHUNK)  // 196
#define XFORM_BLOCKS ((N_NODES + 63) / 64)               // 782
#define XPAD 68

// bf16 row accumulate: 8 bf16 dims (uint4) into fp32[8]
#define ACC8(vv, A)                                                            \
    do {                                                                       \
        A[0] += __uint_as_float((vv).x << 16);                                 \
        A[1] += __uint_as_float((vv).x & 0xFFFF0000u);                         \
        A[2] += __uint_as_float((vv).y << 16);                                 \
        A[3] += __uint_as_float((vv).y & 0xFFFF0000u);                         \
        A[4] += __uint_as_float((vv).z << 16);                                 \
        A[5] += __uint_as_float((vv).z & 0xFFFF0000u);                         \
        A[6] += __uint_as_float((vv).w << 16);                                 \
        A[7] += __uint_as_float((vv).w & 0xFFFF0000u);                         \
    } while (0)

// Build this bucket's CSR in LDS from its ebuf region. All 256 threads.
// Single-pass: each thread holds its <=6 ebuf entries in registers
// (one global latency round instead of two on the block critical path).
__device__ __forceinline__ void build_local_csr(
    int bucket, const int* __restrict__ cnt, const int* __restrict__ ebuf,
    unsigned short* lcsr, int* nhist, int* sval, int* sexcl, int* ncur) {
    int tid = threadIdx.x;
    int bs = bucket * BKT_CAP;
    int ne = min(cnt[bucket * CNT_STRIDE], BKT_CAP);   // defensive clamp
    if (tid < BKT_NODES) { nhist[tid] = 0; ncur[tid] = 0; }
    __syncthreads();
    int held[6];                 // 6*256 = 1536 >= BKT_CAP
    int nh = 0;
    for (int i = tid; i < ne; i += 256) held[nh++] = ebuf[bs + i];
#pragma unroll
    for (int j = 0; j < 6; j++)
        if (j < nh) atomicAdd(&nhist[held[j] >> 16], 1);
    __syncthreads();
    if (tid < 64) {            // wave 0: inclusive scan via shfl_up
        int v = nhist[tid];
        int s = v;
#pragma unroll
        for (int off = 1; off < 64; off <<= 1) {
            int u = __shfl_up(s, off, 64);
            if (tid >= off) s += u;
        }
        sval[tid] = v;
        sexcl[tid] = s - v;
    }
    __syncthreads();
#pragma unroll
    for (int j = 0; j < 6; j++)
        if (j < nh) {
            int p = held[j];
            int l = p >> 16;
            int r = atomicAdd(&ncur[l], 1);
            lcsr[sexcl[l] + r] = (unsigned short)(p & 0xFFFF);
        }
    __syncthreads();
}

// Dual-node mean aggregation: both nodes' chunks in flight (16 outstanding
// 16B gathers) to double memory-level parallelism vs sequential nodes.
__device__ __forceinline__ void agg2(
    int sA, int dA, int sB, int dB, int sl,
    const unsigned short* lcsr, const __hip_bfloat16* __restrict__ Pb,
    float oA[8], float oB[8]) {
    float a0[8], a1[8], b0[8], b1[8];
#pragma unroll
    for (int j = 0; j < 8; j++) { a0[j] = 0.f; a1[j] = 0.f; b0[j] = 0.f; b1[j] = 0.f; }
    int eA = sA + dA, eB = sB + dB;
    int pA = sA, pB = sB;
    while ((pA + 8 <= eA) && (pB + 8 <= eB)) {
        uint4 vA[8], vB[8];
#pragma unroll
        for (int j = 0; j < 8; j++)
            vA[j] = ((const uint4*)(Pb + (size_t)lcsr[pA + j] * 64))[sl];
#pragma unroll
        for (int j = 0; j < 8; j++)
            vB[j] = ((const uint4*)(Pb + (size_t)lcsr[pB + j] * 64))[sl];
#pragma unroll
        for (int j = 0; j < 8; j++) ACC8(vA[j], ((j & 1) ? a1 : a0));
#pragma unroll
        for (int j = 0; j < 8; j++) ACC8(vB[j], ((j & 1) ? b1 : b0));
        pA += 8; pB += 8;
    }
    while (pA + 8 <= eA) {
        uint4 v[8];
#pragma unroll
        for (int j = 0; j < 8; j++)
            v[j] = ((const uint4*)(Pb + (size_t)lcsr[pA + j] * 64))[sl];
#pragma unroll
        for (int j = 0; j < 8; j++) ACC8(v[j], ((j & 1) ? a1 : a0));
        pA += 8;
    }
    while (pB + 8 <= eB) {
        uint4 v[8];
#pragma unroll
        for (int j = 0; j < 8; j++)
            v[j] = ((const uint4*)(Pb + (size_t)lcsr[pB + j] * 64))[sl];
#pragma unroll
        for (int j = 0; j < 8; j++) ACC8(v[j], ((j & 1) ? b1 : b0));
        pB += 8;
    }
    for (; pA < eA; ++pA) {
        uint4 v = ((const uint4*)(Pb + (size_t)lcsr[pA] * 64))[sl];
        ACC8(v, a0);
    }
    for (; pB < eB; ++pB) {
        uint4 v = ((const uint4*)(Pb + (size_t)lcsr[pB] * 64))[sl];
        ACC8(v, b0);
    }
    float invA = (dA > 0) ? 1.0f / (float)dA : 0.0f;
    float invB = (dB > 0) ? 1.0f / (float)dB : 0.0f;
#pragma unroll
    for (int j = 0; j < 8; j++) {
        oA[j] = (a0[j] + a1[j]) * invA;
        oB[j] = (b0[j] + b1[j]) * invB;
    }
}

// m += Q (from H), relu, stage 8 dims into dst[sl*8..sl*8+7]
__device__ __forceinline__ void finish_row(int node, int sl,
                                           const float* __restrict__ H,
                                           float m[8], float* dst) {
    if (node < N_NODES) {
        size_t off = (size_t)node * 64 + sl * 8;
        float4 q0 = *(const float4*)&H[off];
        float4 q1 = *(const float4*)&H[off + 4];
        m[0] = fmaxf(m[0] + q0.x, 0.f);
        m[1] = fmaxf(m[1] + q0.y, 0.f);
        m[2] = fmaxf(m[2] + q0.z, 0.f);
        m[3] = fmaxf(m[3] + q0.w, 0.f);
        m[4] = fmaxf(m[4] + q1.x, 0.f);
        m[5] = fmaxf(m[5] + q1.y, 0.f);
        m[6] = fmaxf(m[6] + q1.z, 0.f);
        m[7] = fmaxf(m[7] + q1.w, 0.f);
    } else {
#pragma unroll
        for (int j = 0; j < 8; j++) m[j] = 0.f;
    }
    *(float4*)&dst[sl * 8] = make_float4(m[0], m[1], m[2], m[3]);
    *(float4*)&dst[sl * 8 + 4] = make_float4(m[4], m[5], m[6], m[7]);
}

// ---------------- combo: bucket multi-split (blocks 0..EB) + layer-0 xform ----------------
__global__ __launch_bounds__(256) void k_combo(
    const int* __restrict__ esrc, const int* __restrict__ edst,
    int* __restrict__ cnt, int* __restrict__ ebuf,
    const int* __restrict__ ids, const float* __restrict__ emb,
    const float* __restrict__ Wl, const float* __restrict__ bl,
    const float* __restrict__ Wr,
    __hip_bfloat16* __restrict__ Pb, float* __restrict__ Qout) {
    __shared__ float sW[64 * 64];
    __shared__ float sX[64 * XPAD];
    int t = threadIdx.x;
    if (blockIdx.x < EB_BLOCKS) {
        // ---- bsplit path: alias LDS as int scratch ----
        // Single-pass over edst: dests held in registers across hist+scatter.
        int* h = (int*)sW;                 // NB_BKT
        int* bbase = h + NB_BKT;           // NB_BKT
        int* cur = (int*)sX;               // NB_BKT
        for (int i = t; i < NB_BKT; i += 256) { h[i] = 0; cur[i] = 0; }
        __syncthreads();
        int base = blockIdx.x * EB_CHUNK;
        int end = min(base + EB_CHUNK, N_EDGES);
        int dreg[EB_PER_THR];
        int nd = 0;
        for (int i = base + t; i < end; i += 256) dreg[nd++] = edst[i];
#pragma unroll
        for (int j = 0; j < EB_PER_THR; j++)
            if (j < nd) atomicAdd(&h[dreg[j] >> BKT_SHIFT], 1);
        __syncthreads();
        for (int i = t; i < NB_BKT; i += 256)
            if (h[i]) bbase[i] = i * BKT_CAP + atomicAdd(&cnt[i * CNT_STRIDE], h[i]);
        __syncthreads();
        {
            int j = 0;
            for (int i = base + t; i < end; i += 256, j++) {
                int d = dreg[j], s = esrc[i];
                int b = d >> BKT_SHIFT;
                int r = atomicAdd(&cur[b], 1);
                int slot = bbase[b] + r;
                if (slot < (b + 1) * BKT_CAP)          // defensive clamp
                    ebuf[slot] = ((d & (BKT_NODES - 1)) << 16) | s;
            }
        }
        return;
    }
    // ---- xform0 path (two-pass W staging) ----
    int tile = (blockIdx.x - EB_BLOCKS) * 64;
    for (int i = t; i < 64 * 16; i += 256)
        ((float4*)sW)[i] = ((const float4*)Wl)[i];
    for (int i = t; i < 64 * 16; i += 256) {
        int r = i >> 4, c = i & 15;
        int node = tile + r;
        float4 v = make_float4(0.f, 0.f, 0.f, 0.f);
        if (node < N_NODES)
            v = ((const float4*)(emb + (size_t)ids[node] * 64))[c];
        *(float4*)&sX[r * XPAD + c * 4] = v;
    }
    __syncthreads();
    int dg = t & 15, ng = t >> 4;
    float acc[4][4];
#pragma unroll
    for (int i = 0; i < 4; i++)
#pragma unroll
        for (int j = 0; j < 4; j++) acc[i][j] = 0.f;
#pragma unroll 4
    for (int k = 0; k < 64; k++) {
        float4 w = *(const float4*)&sW[k * 64 + dg * 4];
#pragma unroll
        for (int i = 0; i < 4; i++) {
            float xv = sX[(ng + i * 16) * XPAD + k];
            acc[i][0] = fmaf(xv, w.x, acc[i][0]);
            acc[i][1] = fmaf(xv, w.y, acc[i][1]);
            acc[i][2] = fmaf(xv, w.z, acc[i][2]);
            acc[i][3] = fmaf(xv, w.w, acc[i][3]);
        }
    }
#pragma unroll
    for (int i = 0; i < 4; i++) {
        int node = tile + ng + i * 16;
        if (node < N_NODES) {
            union { ushort4 u; __hip_bfloat16 h[4]; } pk;
            pk.h[0] = __float2bfloat16(acc[i][0]);
            pk.h[1] = __float2bfloat16(acc[i][1]);
            pk.h[2] = __float2bfloat16(acc[i][2]);
            pk.h[3] = __float2bfloat16(acc[i][3]);
            *(ushort4*)&Pb[(size_t)node * 64 + dg * 4] = pk.u;
        }
    }
    __syncthreads();
    for (int i = t; i < 64 * 16; i += 256)
        ((float4*)sW)[i] = ((const float4*)Wr)[i];
    __syncthreads();
#pragma unroll
    for (int i = 0; i < 4; i++)
#pragma unroll
        for (int j = 0; j < 4; j++) acc[i][j] = 0.f;
#pragma unroll 4
    for (int k = 0; k < 64; k++) {
        float4 w = *(const float4*)&sW[k * 64 + dg * 4];
#pragma unroll
        for (int i = 0; i < 4; i++) {
            float xv = sX[(ng + i * 16) * XPAD + k];
            acc[i][0] = fmaf(xv, w.x, acc[i][0]);
            acc[i][1] = fmaf(xv, w.y, acc[i][1]);
            acc[i][2] = fmaf(xv, w.z, acc[i][2]);
            acc[i][3] = fmaf(xv, w.w, acc[i][3]);
        }
    }
    float4 blv = *(const float4*)&bl[dg * 4];
#pragma unroll
    for (int i = 0; i < 4; i++) {
        int node = tile + ng + i * 16;
        if (node < N_NODES)
            *(float4*)&Qout[(size_t)node * 64 + dg * 4] =
                make_float4(acc[i][0] + blv.x, acc[i][1] + blv.y,
                            acc[i][2] + blv.z, acc[i][3] + blv.w);
    }
}

// ---------------- fused: LDS CSR + layer-0 aggregate + layer-1 xform ----------------
__global__ __launch_bounds__(256, 4) void k_fused1(
    const int* __restrict__ cnt, const int* __restrict__ ebuf,
    const __hip_bfloat16* __restrict__ Pb0, const float* __restrict__ Wl,
    const float* __restrict__ bl, const float* __restrict__ Wr,
    __hip_bfloat16* __restrict__ Pb1, float* __restrict__ H) {
    __shared__ float sW[64 * 64];
    __shared__ float sX[64 * XPAD];
    __shared__ unsigned short lcsr[BKT_CAP];
    __shared__ int nhist[BKT_NODES], sval[BKT_NODES], sexcl[BKT_NODES], ncur[BKT_NODES];
    int t = threadIdx.x;
    int tile = blockIdx.x * 64;
    // Wl prefetch issues early; hides behind CSR build + gather
    for (int i = t; i < 64 * 16; i += 256)
        ((float4*)sW)[i] = ((const float4*)Wl)[i];
    build_local_csr(blockIdx.x, cnt, ebuf, lcsr, nhist, sval, sexcl, ncur);
    // phase (a): dual-node aggregate per eighth-wave, H0 = relu(mean+Q0) -> sX
    int grp = t >> 3, sl = t & 7;
    int ln0 = grp * 2, ln1 = ln0 + 1;
    float mA[8], mB[8];
    agg2(sexcl[ln0], sval[ln0], sexcl[ln1], sval[ln1], sl, lcsr, Pb0, mA, mB);
    finish_row(tile + ln0, sl, H, mA, &sX[ln0 * XPAD]);
    finish_row(tile + ln1, sl, H, mB, &sX[ln1 * XPAD]);
    __syncthreads();
    // phase (b1): Pb1 = H0 @ Wl
    int dg = t & 15, ng = t >> 4;
    float acc[4][4];
#pragma unroll
    for (int i = 0; i < 4; i++)
#pragma unroll
        for (int j = 0; j < 4; j++) acc[i][j] = 0.f;
#pragma unroll 4
    for (int k = 0; k < 64; k++) {
        float4 w = *(const float4*)&sW[k * 64 + dg * 4];
#pragma unroll
        for (int i = 0; i < 4; i++) {
            float xv = sX[(ng + i * 16) * XPAD + k];
            acc[i][0] = fmaf(xv, w.x, acc[i][0]);
            acc[i][1] = fmaf(xv, w.y, acc[i][1]);
            acc[i][2] = fmaf(xv, w.z, acc[i][2]);
            acc[i][3] = fmaf(xv, w.w, acc[i][3]);
        }
    }
#pragma unroll
    for (int i = 0; i < 4; i++) {
        int node = tile + ng + i * 16;
        if (node < N_NODES) {
            union { ushort4 u; __hip_bfloat16 h[4]; } pk;
            pk.h[0] = __float2bfloat16(acc[i][0]);
            pk.h[1] = __float2bfloat16(acc[i][1]);
            pk.h[2] = __float2bfloat16(acc[i][2]);
            pk.h[3] = __float2bfloat16(acc[i][3]);
            *(ushort4*)&Pb1[(size_t)node * 64 + dg * 4] = pk.u;
        }
    }
    __syncthreads();
    for (int i = t; i < 64 * 16; i += 256)
        ((float4*)sW)[i] = ((const float4*)Wr)[i];
    __syncthreads();
    // phase (b2): H = Q1 = H0 @ Wr + bl
#pragma unroll
    for (int i = 0; i < 4; i++)
#pragma unroll
        for (int j = 0; j < 4; j++) acc[i][j] = 0.f;
#pragma unroll 4
    for (int k = 0; k < 64; k++) {
        float4 w = *(const float4*)&sW[k * 64 + dg * 4];
#pragma unroll
        for (int i = 0; i < 4; i++) {
            float xv = sX[(ng + i * 16) * XPAD + k];
            acc[i][0] = fmaf(xv, w.x, acc[i][0]);
            acc[i][1] = fmaf(xv, w.y, acc[i][1]);
            acc[i][2] = fmaf(xv, w.z, acc[i][2]);
            acc[i][3] = fmaf(xv, w.w, acc[i][3]);
        }
    }
    float4 blv = *(const float4*)&bl[dg * 4];
#pragma unroll
    for (int i = 0; i < 4; i++) {
        int node = tile + ng + i * 16;
        if (node < N_NODES)
            *(float4*)&H[(size_t)node * 64 + dg * 4] =
                make_float4(acc[i][0] + blv.x, acc[i][1] + blv.y,
                            acc[i][2] + blv.z, acc[i][3] + blv.w);
    }
}

// ---------------- layer-1 aggregate + pooling (block = bucket = 64 nodes) ----------------
// Stage relu rows in LDS, then per-dim segmented sum (batch sorted) ->
// coalesced global atomics.
__global__ __launch_bounds__(256, 4) void k_agg2_pool(
    const int* __restrict__ cnt, const int* __restrict__ ebuf,
    const __hip_bfloat16* __restrict__ Pb, const float* __restrict__ H,
    const int* __restrict__ batch, float* __restrict__ psum) {
    __shared__ float sPool[64 * 64];
    __shared__ unsigned short lcsr[BKT_CAP];
    __shared__ int nhist[BKT_NODES], sval[BKT_NODES], sexcl[BKT_NODES], ncur[BKT_NODES];
    __shared__ int sLg[64];
    int t = threadIdx.x;
    int nb = blockIdx.x * 64;
    int gmin = batch[nb];
    if (t < 64) {
        int node = nb + t;
        sLg[t] = batch[node < N_NODES ? node : (N_NODES - 1)] - gmin;
    }
    build_local_csr(blockIdx.x, cnt, ebuf, lcsr, nhist, sval, sexcl, ncur);
    int grp = t >> 3, sl = t & 7;
    int ln0 = grp * 2, ln1 = ln0 + 1;
    float mA[8], mB[8];
    agg2(sexcl[ln0], sval[ln0], sexcl[ln1], sval[ln1], sl, lcsr, Pb, mA, mB);
    finish_row(nb + ln0, sl, H, mA, &sPool[ln0 * 64]);
    finish_row(nb + ln1, sl, H, mB, &sPool[ln1 * 64]);
    __syncthreads();
    // segmented per-dim sum over this bucket's 64 rows (batch sorted -> lg
    // non-decreasing). Each thread owns one dim x one 16-node quarter.
    int d = t & 63, q = t >> 6;
    int n0 = q * 16;
    float run = 0.f;
    int cur = sLg[n0];
    for (int n = n0; n < n0 + 16; n++) {
        int lg = sLg[n];
        if (lg != cur) {
            if (run != 0.f)
                atomicAdd(&psum[(size_t)(gmin + cur) * 64 + d], run);
            run = 0.f;
            cur = lg;
        }
        run += sPool[n * 64 + d];
    }
    if (run != 0.f)
        atomicAdd(&psum[(size_t)(gmin + cur) * 64 + d], run);
}

// ---------------- output projection ----------------
__device__ __forceinline__ int lower_bound_batch(const int* __restrict__ batch, int val) {
    int lo = 0, hi = N_NODES;
    while (lo < hi) {
        int mid = (lo + hi) >> 1;
        if (batch[mid] < val) lo = mid + 1; else hi = mid;
    }
    return lo;
}

__global__ __launch_bounds__(256) void k_out(
    const int* __restrict__ batch, const float* __restrict__ psum,
    const float* __restrict__ Wout, const float* __restrict__ bout,
    float* __restrict__ out) {
    int w = threadIdx.x >> 6, lane = threadIdx.x & 63;
    int g = blockIdx.x * 4 + w;
    if (g >= N_GRAPHS) return;
    int s0 = lower_bound_batch(batch, g);
    int s1 = lower_bound_batch(batch, g + 1);
    int cntg = s1 - s0;
    float inv = (cntg > 0) ? 1.0f / (float)cntg : 0.0f;
    float pooled = psum[(size_t)g * 64 + lane] * inv;
#pragma unroll
    for (int c = 0; c < N_CLASSES; c++) {
        float v = pooled * Wout[lane * N_CLASSES + c];
#pragma unroll
        for (int off = 32; off > 0; off >>= 1) v += __shfl_down(v, off, 64);
        if (lane == 0) out[(size_t)g * N_CLASSES + c] = v + bout[c];
    }
}

// ---------------- launch ----------------

extern "C" void kernel_launch(void* const* d_in, const int* in_sizes, int n_in,
                              void* d_out, int out_size, void* d_ws, size_t ws_size,
                              hipStream_t stream) {
    const int*   node_ids = (const int*)d_in[0];
    const int*   edge_idx = (const int*)d_in[1];   // [2, E] row-major
    const int*   batch    = (const int*)d_in[2];
    const float* emb      = (const float*)d_in[3];
    const float* Wl0      = (const float*)d_in[4];
    const float* bl0      = (const float*)d_in[5];
    const float* Wr0      = (const float*)d_in[6];
    const float* Wl1      = (const float*)d_in[7];
    const float* bl1      = (const float*)d_in[8];
    const float* Wr1      = (const float*)d_in[9];
    const float* Wout     = (const float*)d_in[10];
    const float* bout     = (const float*)d_in[11];
    float* out = (float*)d_out;

    const int* esrc = edge_idx;
    const int* edst = edge_idx + N_EDGES;

    // workspace layout
    __hip_bfloat16* Pb0 = (__hip_bfloat16*)d_ws;              // N*64 bf16
    __hip_bfloat16* Pb1 = Pb0 + (size_t)N_NODES * 64;         // N*64 bf16
    float* H = (float*)(Pb1 + (size_t)N_NODES * 64);          // N*64 f32
    int* ebuf = (int*)(H + (size_t)N_NODES * 64);             // NB*CAP ints
    int* cnt = ebuf + (size_t)NB_BKT * BKT_CAP;               // NB*CNT_STRIDE ints
    float* psum = (float*)(cnt + (size_t)NB_BKT * CNT_STRIDE); // G*64 floats (contiguous w/ cnt)

    const int BLK = 256;

    // one memset zeroes padded bucket counters + pool accumulators (contiguous)
    hipMemsetAsync(cnt, 0, (NB_BKT * CNT_STRIDE + N_GRAPHS * 64) * sizeof(int), stream);

    // combo: bucket multi-split (196 blocks) + layer-0 xform (782 blocks)
    k_combo<<<EB_BLOCKS + XFORM_BLOCKS, BLK, 0, stream>>>(
        esrc, edst, cnt, ebuf, node_ids, emb, Wl0, bl0, Wr0, Pb0, H);

    // fused layer-0 aggregate (LDS CSR) + layer-1 transform
    k_fused1<<<XFORM_BLOCKS, BLK, 0, stream>>>(cnt, ebuf, Pb0, Wl1, bl1, Wr1, Pb1, H);

    // layer-1 aggregate (LDS CSR) fused with graph pooling
    k_agg2_pool<<<NB_BKT, BLK, 0, stream>>>(cnt, ebuf, Pb1, H, batch, psum);

    // output projection
    k_out<<<(N_GRAPHS + 3) / 4, BLK, 0, stream>>>(batch, psum, Wout, bout, out);
}

// Round 5
// 183.656 us; speedup vs baseline: 2.5082x; 1.0254x over previous
//
#include <hip/hip_runtime.h>
#include <hip/hip_bf16.h>

#define N_NODES 50000
#define N_EDGES 800000
#define EMB 64
#define HID 64
#define N_CLASSES 10
#define N_GRAPHS 512

#define BKT_SHIFT 6
#define BKT_NODES 64
#define NB_BKT ((N_NODES + BKT_NODES - 1) / BKT_NODES)   // 782
#define BKT_CAP 1408     // mean 1024 + 12 sigma
#define CNT_STRIDE 16    // one counter per 64B line: kills cross-XCD false sharing
#define EB_CHUNK 4096
#define EB_PER_THR (EB_CHUNK / 256)                      // 16
#define EB_BLOCKS ((N_EDGES + EB_CHUNK - 1) / EB_CHUNK)  // 196
#define XFORM_BLOCKS ((N_NODES + 63) / 64)               // 782
#define XPAD 68
#define ZROW N_NODES                                      // sentinel zero-row in Pb
#define LCSR_SZ 1856      // sum of 8-aligned padded degrees: 1408 + 64*7
#define LCSR_FULL 1864    // +8 guard so clamped loads of empty regions stay in-array

// bf16 row accumulate: 8 bf16 dims (uint4) into fp32[8]
#define ACC8(vv, A)                                                            \
    do {                                                                       \
        A[0] += __uint_as_float((vv).x << 16);                                 \
        A[1] += __uint_as_float((vv).x & 0xFFFF0000u);                         \
        A[2] += __uint_as_float((vv).y << 16);                                 \
        A[3] += __uint_as_float((vv).y & 0xFFFF0000u);                         \
        A[4] += __uint_as_float((vv).z << 16);                                 \
        A[5] += __uint_as_float((vv).z & 0xFFFF0000u);                         \
        A[6] += __uint_as_float((vv).w << 16);                                 \
        A[7] += __uint_as_float((vv).w & 0xFFFF0000u);                         \
    } while (0)

// Build this bucket's CSR in LDS. Regions 8-aligned, pads = ZROW sentinel
// (points at a zeroed Pb row) -> branch-free chunked aggregation.
__device__ __forceinline__ void build_local_csr(
    int bucket, const int* __restrict__ cnt, const int* __restrict__ ebuf,
    unsigned short* lcsr, int* nhist, int* sval, int* sexcl, int* ncur) {
    int tid = threadIdx.x;
    int bs = bucket * BKT_CAP;
    int ne = min(cnt[bucket * CNT_STRIDE], BKT_CAP);   // defensive clamp
    if (tid < BKT_NODES) { nhist[tid] = 0; ncur[tid] = 0; }
    for (int i = tid; i < LCSR_FULL; i += 256) lcsr[i] = (unsigned short)ZROW;
    __syncthreads();
    int held[6];                 // 6*256 = 1536 >= BKT_CAP
    int nh = 0;
    for (int i = tid; i < ne; i += 256) held[nh++] = ebuf[bs + i];
#pragma unroll
    for (int j = 0; j < 6; j++)
        if (j < nh) atomicAdd(&nhist[held[j] >> 16], 1);
    __syncthreads();
    if (tid < 64) {            // wave 0: scan of PADDED degrees for offsets
        int v = nhist[tid];
        int p = (v + 7) & ~7;
        int s = p;
#pragma unroll
        for (int off = 1; off < 64; off <<= 1) {
            int u = __shfl_up(s, off, 64);
            if (tid >= off) s += u;
        }
        sval[tid] = v;
        sexcl[tid] = s - p;
    }
    __syncthreads();
#pragma unroll
    for (int j = 0; j < 6; j++)
        if (j < nh) {
            int p = held[j];
            int l = p >> 16;
            int r = atomicAdd(&ncur[l], 1);
            lcsr[sexcl[l] + r] = (unsigned short)(p & 0xFFFF);
        }
    __syncthreads();
}

// Dual-node mean aggregation, 4-wide chunks, 2-deep software pipeline:
// chunk c+1's 8 loads are in flight while chunk c accumulates.
// Sentinel-padded CSR -> no tails; clamped loads + predicated ACC.
__device__ __forceinline__ void agg2(
    int sA, int dA, int sB, int dB, int sl,
    const unsigned short* lcsr, const __hip_bfloat16* __restrict__ Pb,
    float oA[8], float oB[8]) {
    float a0[8], a1[8], b0[8], b1[8];
#pragma unroll
    for (int j = 0; j < 8; j++) { a0[j] = 0.f; a1[j] = 0.f; b0[j] = 0.f; b1[j] = 0.f; }
    int nA = (dA + 3) >> 2, nB = (dB + 3) >> 2;
    int n = max(nA, nB);
    int mA = max(nA - 1, 0), mB = max(nB - 1, 0);
    if (n > 0) {
        uint4 A0[4], A1[4], B0[4], B1[4];
#define LD4(D, base_)                                                          \
        {                                                                      \
            int _p = (base_);                                                  \
            D[0] = ((const uint4*)(Pb + (size_t)lcsr[_p + 0] * 64))[sl];       \
            D[1] = ((const uint4*)(Pb + (size_t)lcsr[_p + 1] * 64))[sl];       \
            D[2] = ((const uint4*)(Pb + (size_t)lcsr[_p + 2] * 64))[sl];       \
            D[3] = ((const uint4*)(Pb + (size_t)lcsr[_p + 3] * 64))[sl];       \
        }
#define AC4(S, X0, X1)                                                         \
        { ACC8(S[0], X0); ACC8(S[1], X1); ACC8(S[2], X0); ACC8(S[3], X1); }
        LD4(A0, sA); LD4(B0, sB);
        int c = 1;
        for (; c + 1 < n; c += 2) {
            LD4(A1, sA + 4 * min(c, mA)); LD4(B1, sB + 4 * min(c, mB));
            if (c - 1 < nA) AC4(A0, a0, a1);
            if (c - 1 < nB) AC4(B0, b0, b1);
            LD4(A0, sA + 4 * min(c + 1, mA)); LD4(B0, sB + 4 * min(c + 1, mB));
            if (c < nA) AC4(A1, a0, a1);
            if (c < nB) AC4(B1, b0, b1);
        }
        if (c < n) {
            LD4(A1, sA + 4 * min(c, mA)); LD4(B1, sB + 4 * min(c, mB));
            if (c - 1 < nA) AC4(A0, a0, a1);
            if (c - 1 < nB) AC4(B0, b0, b1);
            if (c < nA) AC4(A1, a0, a1);
            if (c < nB) AC4(B1, b0, b1);
        } else {
            if (c - 1 < nA) AC4(A0, a0, a1);
            if (c - 1 < nB) AC4(B0, b0, b1);
        }
#undef LD4
#undef AC4
    }
    float invA = (dA > 0) ? 1.0f / (float)dA : 0.0f;
    float invB = (dB > 0) ? 1.0f / (float)dB : 0.0f;
#pragma unroll
    for (int j = 0; j < 8; j++) {
        oA[j] = (a0[j] + a1[j]) * invA;
        oB[j] = (b0[j] + b1[j]) * invB;
    }
}

// m += Q (from H), relu, stage 8 dims into dst[sl*8..sl*8+7]
__device__ __forceinline__ void finish_row(int node, int sl,
                                           const float* __restrict__ H,
                                           float m[8], float* dst) {
    if (node < N_NODES) {
        size_t off = (size_t)node * 64 + sl * 8;
        float4 q0 = *(const float4*)&H[off];
        float4 q1 = *(const float4*)&H[off + 4];
        m[0] = fmaxf(m[0] + q0.x, 0.f);
        m[1] = fmaxf(m[1] + q0.y, 0.f);
        m[2] = fmaxf(m[2] + q0.z, 0.f);
        m[3] = fmaxf(m[3] + q0.w, 0.f);
        m[4] = fmaxf(m[4] + q1.x, 0.f);
        m[5] = fmaxf(m[5] + q1.y, 0.f);
        m[6] = fmaxf(m[6] + q1.z, 0.f);
        m[7] = fmaxf(m[7] + q1.w, 0.f);
    } else {
#pragma unroll
        for (int j = 0; j < 8; j++) m[j] = 0.f;
    }
    *(float4*)&dst[sl * 8] = make_float4(m[0], m[1], m[2], m[3]);
    *(float4*)&dst[sl * 8 + 4] = make_float4(m[4], m[5], m[6], m[7]);
}

// Fused dual-weight 64x64x64 GEMM from staged sX. Weights read from global
// (L1-resident 16KB each, 256B/wave/instruction). One barrier-free pass:
// Pb = bf16(sX @ Wl)  and  Qout = sX @ Wr + bl.
__device__ __forceinline__ void gemm_dual_from_sX(
    int tile, int t, const float* sX,
    const float* __restrict__ Wl, const float* __restrict__ Wr,
    const float* __restrict__ bl,
    __hip_bfloat16* __restrict__ Pb, float* __restrict__ Qout) {
    int dg = t & 15, ng = t >> 4;
    float accL[4][4], accR[4][4];
#pragma unroll
    for (int i = 0; i < 4; i++)
#pragma unroll
        for (int j = 0; j < 4; j++) { accL[i][j] = 0.f; accR[i][j] = 0.f; }
#pragma unroll 4
    for (int k = 0; k < 64; k++) {
        float4 wl = ((const float4*)Wl)[k * 16 + dg];
        float4 wr = ((const float4*)Wr)[k * 16 + dg];
#pragma unroll
        for (int i = 0; i < 4; i++) {
            float xv = sX[(ng + i * 16) * XPAD + k];
            accL[i][0] = fmaf(xv, wl.x, accL[i][0]);
            accL[i][1] = fmaf(xv, wl.y, accL[i][1]);
            accL[i][2] = fmaf(xv, wl.z, accL[i][2]);
            accL[i][3] = fmaf(xv, wl.w, accL[i][3]);
            accR[i][0] = fmaf(xv, wr.x, accR[i][0]);
            accR[i][1] = fmaf(xv, wr.y, accR[i][1]);
            accR[i][2] = fmaf(xv, wr.z, accR[i][2]);
            accR[i][3] = fmaf(xv, wr.w, accR[i][3]);
        }
    }
    float4 blv = ((const float4*)bl)[dg];
#pragma unroll
    for (int i = 0; i < 4; i++) {
        int node = tile + ng + i * 16;
        if (node < N_NODES) {
            union { ushort4 u; __hip_bfloat16 h[4]; } pk;
            pk.h[0] = __float2bfloat16(accL[i][0]);
            pk.h[1] = __float2bfloat16(accL[i][1]);
            pk.h[2] = __float2bfloat16(accL[i][2]);
            pk.h[3] = __float2bfloat16(accL[i][3]);
            *(ushort4*)&Pb[(size_t)node * 64 + dg * 4] = pk.u;
            *(float4*)&Qout[(size_t)node * 64 + dg * 4] =
                make_float4(accR[i][0] + blv.x, accR[i][1] + blv.y,
                            accR[i][2] + blv.z, accR[i][3] + blv.w);
        }
    }
}

// ---------------- combo: bucket multi-split (blocks 0..EB) + layer-0 xform ----------------
__global__ __launch_bounds__(256) void k_combo(
    const int* __restrict__ esrc, const int* __restrict__ edst,
    int* __restrict__ cnt, int* __restrict__ ebuf,
    const int* __restrict__ ids, const float* __restrict__ emb,
    const float* __restrict__ Wl, const float* __restrict__ bl,
    const float* __restrict__ Wr,
    __hip_bfloat16* __restrict__ Pb, __hip_bfloat16* __restrict__ Pb1z,
    float* __restrict__ Qout) {
    __shared__ float sX[64 * XPAD];     // bsplit path aliases as int scratch
    int t = threadIdx.x;
    if (blockIdx.x < EB_BLOCKS) {
        // block 0 additionally zeroes the Pb0/Pb1 sentinel rows (ZROW)
        if (blockIdx.x == 0 && t < 16) {
            uint4 z = make_uint4(0u, 0u, 0u, 0u);
            if (t < 8) ((uint4*)(Pb + (size_t)ZROW * 64))[t] = z;
            else       ((uint4*)(Pb1z + (size_t)ZROW * 64))[t - 8] = z;
        }
        // ---- bsplit path (single pass over edst; dests in registers) ----
        int* h = (int*)sX;                 // NB_BKT
        int* bbase = h + NB_BKT;           // NB_BKT
        int* cur = bbase + NB_BKT;         // NB_BKT  (3*782*4 = 9.4KB < 17.4KB)
        for (int i = t; i < NB_BKT; i += 256) { h[i] = 0; cur[i] = 0; }
        __syncthreads();
        int base = blockIdx.x * EB_CHUNK;
        int end = min(base + EB_CHUNK, N_EDGES);
        int dreg[EB_PER_THR];
        int nd = 0;
        for (int i = base + t; i < end; i += 256) dreg[nd++] = edst[i];
#pragma unroll
        for (int j = 0; j < EB_PER_THR; j++)
            if (j < nd) atomicAdd(&h[dreg[j] >> BKT_SHIFT], 1);
        __syncthreads();
        for (int i = t; i < NB_BKT; i += 256)
            if (h[i]) bbase[i] = i * BKT_CAP + atomicAdd(&cnt[i * CNT_STRIDE], h[i]);
        __syncthreads();
        {
            int j = 0;
            for (int i = base + t; i < end; i += 256, j++) {
                int d = dreg[j], s = esrc[i];
                int b = d >> BKT_SHIFT;
                int r = atomicAdd(&cur[b], 1);
                int slot = bbase[b] + r;
                if (slot < (b + 1) * BKT_CAP)          // defensive clamp
                    ebuf[slot] = ((d & (BKT_NODES - 1)) << 16) | s;
            }
        }
        return;
    }
    // ---- xform0 path: stage emb rows, fused dual GEMM ----
    int tile = (blockIdx.x - EB_BLOCKS) * 64;
    for (int i = t; i < 64 * 16; i += 256) {
        int r = i >> 4, c = i & 15;
        int node = tile + r;
        float4 v = make_float4(0.f, 0.f, 0.f, 0.f);
        if (node < N_NODES)
            v = ((const float4*)(emb + (size_t)ids[node] * 64))[c];
        *(float4*)&sX[r * XPAD + c * 4] = v;
    }
    __syncthreads();
    gemm_dual_from_sX(tile, t, sX, Wl, Wr, bl, Pb, Qout);
}

// ---------------- fused: LDS CSR + layer-0 aggregate + layer-1 xform ----------------
__global__ __launch_bounds__(256, 4) void k_fused1(
    const int* __restrict__ cnt, const int* __restrict__ ebuf,
    const __hip_bfloat16* __restrict__ Pb0, const float* __restrict__ Wl,
    const float* __restrict__ bl, const float* __restrict__ Wr,
    __hip_bfloat16* __restrict__ Pb1, float* __restrict__ H) {
    __shared__ float sX[64 * XPAD];
    __shared__ unsigned short lcsr[LCSR_FULL];
    __shared__ int nhist[BKT_NODES], sval[BKT_NODES], sexcl[BKT_NODES], ncur[BKT_NODES];
    int t = threadIdx.x;
    int tile = blockIdx.x * 64;
    build_local_csr(blockIdx.x, cnt, ebuf, lcsr, nhist, sval, sexcl, ncur);
    // phase (a): pipelined dual-node aggregate, H0 = relu(mean+Q0) -> sX
    int grp = t >> 3, sl = t & 7;
    int ln0 = grp * 2, ln1 = ln0 + 1;
    float mA[8], mB[8];
    agg2(sexcl[ln0], sval[ln0], sexcl[ln1], sval[ln1], sl, lcsr, Pb0, mA, mB);
    finish_row(tile + ln0, sl, H, mA, &sX[ln0 * XPAD]);
    finish_row(tile + ln1, sl, H, mB, &sX[ln1 * XPAD]);
    __syncthreads();
    // phase (b): fused dual GEMM -> Pb1 (bf16) and H (Q1)
    gemm_dual_from_sX(tile, t, sX, Wl, Wr, bl, Pb1, H);
}

// ---------------- layer-1 aggregate + pooling (block = bucket = 64 nodes) ----------------
__global__ __launch_bounds__(256, 4) void k_agg2_pool(
    const int* __restrict__ cnt, const int* __restrict__ ebuf,
    const __hip_bfloat16* __restrict__ Pb, const float* __restrict__ H,
    const int* __restrict__ batch, float* __restrict__ psum) {
    __shared__ float sPool[64 * 64];
    __shared__ unsigned short lcsr[LCSR_FULL];
    __shared__ int nhist[BKT_NODES], sval[BKT_NODES], sexcl[BKT_NODES], ncur[BKT_NODES];
    __shared__ int sLg[64];
    int t = threadIdx.x;
    int nb = blockIdx.x * 64;
    int gmin = batch[nb];
    if (t < 64) {
        int node = nb + t;
        sLg[t] = batch[node < N_NODES ? node : (N_NODES - 1)] - gmin;
    }
    build_local_csr(blockIdx.x, cnt, ebuf, lcsr, nhist, sval, sexcl, ncur);
    int grp = t >> 3, sl = t & 7;
    int ln0 = grp * 2, ln1 = ln0 + 1;
    float mA[8], mB[8];
    agg2(sexcl[ln0], sval[ln0], sexcl[ln1], sval[ln1], sl, lcsr, Pb, mA, mB);
    finish_row(nb + ln0, sl, H, mA, &sPool[ln0 * 64]);
    finish_row(nb + ln1, sl, H, mB, &sPool[ln1 * 64]);
    __syncthreads();
    // segmented per-dim sum over this bucket's 64 rows (batch sorted).
    int d = t & 63, q = t >> 6;
    int n0 = q * 16;
    float run = 0.f;
    int cur = sLg[n0];
    for (int n = n0; n < n0 + 16; n++) {
        int lg = sLg[n];
        if (lg != cur) {
            if (run != 0.f)
                atomicAdd(&psum[(size_t)(gmin + cur) * 64 + d], run);
            run = 0.f;
            cur = lg;
        }
        run += sPool[n * 64 + d];
    }
    if (run != 0.f)
        atomicAdd(&psum[(size_t)(gmin + cur) * 64 + d], run);
}

// ---------------- output projection ----------------
__device__ __forceinline__ int lower_bound_batch(const int* __restrict__ batch, int val) {
    int lo = 0, hi = N_NODES;
    while (lo < hi) {
        int mid = (lo + hi) >> 1;
        if (batch[mid] < val) lo = mid + 1; else hi = mid;
    }
    return lo;
}

__global__ __launch_bounds__(256) void k_out(
    const int* __restrict__ batch, const float* __restrict__ psum,
    const float* __restrict__ Wout, const float* __restrict__ bout,
    float* __restrict__ out) {
    int w = threadIdx.x >> 6, lane = threadIdx.x & 63;
    int g = blockIdx.x * 4 + w;
    if (g >= N_GRAPHS) return;
    int s0 = lower_bound_batch(batch, g);
    int s1 = lower_bound_batch(batch, g + 1);
    int cntg = s1 - s0;
    float inv = (cntg > 0) ? 1.0f / (float)cntg : 0.0f;
    float pooled = psum[(size_t)g * 64 + lane] * inv;
#pragma unroll
    for (int c = 0; c < N_CLASSES; c++) {
        float v = pooled * Wout[lane * N_CLASSES + c];
#pragma unroll
        for (int off = 32; off > 0; off >>= 1) v += __shfl_down(v, off, 64);
        if (lane == 0) out[(size_t)g * N_CLASSES + c] = v + bout[c];
    }
}

// ---------------- launch ----------------

extern "C" void kernel_launch(void* const* d_in, const int* in_sizes, int n_in,
                              void* d_out, int out_size, void* d_ws, size_t ws_size,
                              hipStream_t stream) {
    const int*   node_ids = (const int*)d_in[0];
    const int*   edge_idx = (const int*)d_in[1];   // [2, E] row-major
    const int*   batch    = (const int*)d_in[2];
    const float* emb      = (const float*)d_in[3];
    const float* Wl0      = (const float*)d_in[4];
    const float* bl0      = (const float*)d_in[5];
    const float* Wr0      = (const float*)d_in[6];
    const float* Wl1      = (const float*)d_in[7];
    const float* bl1      = (const float*)d_in[8];
    const float* Wr1      = (const float*)d_in[9];
    const float* Wout     = (const float*)d_in[10];
    const float* bout     = (const float*)d_in[11];
    float* out = (float*)d_out;

    const int* esrc = edge_idx;
    const int* edst = edge_idx + N_EDGES;

    // workspace layout (Pb arrays have N+1 rows: last row = ZROW sentinel zeros)
    __hip_bfloat16* Pb0 = (__hip_bfloat16*)d_ws;               // (N+1)*64 bf16
    __hip_bfloat16* Pb1 = Pb0 + (size_t)(N_NODES + 1) * 64;    // (N+1)*64 bf16
    float* H = (float*)(Pb1 + (size_t)(N_NODES + 1) * 64);     // N*64 f32
    int* ebuf = (int*)(H + (size_t)N_NODES * 64);              // NB*CAP ints
    int* cnt = ebuf + (size_t)NB_BKT * BKT_CAP;                // NB*CNT_STRIDE ints
    float* psum = (float*)(cnt + (size_t)NB_BKT * CNT_STRIDE); // G*64 floats

    const int BLK = 256;

    // one memset zeroes padded bucket counters + pool accumulators (contiguous)
    hipMemsetAsync(cnt, 0, (NB_BKT * CNT_STRIDE + N_GRAPHS * 64) * sizeof(int), stream);

    // combo: bucket multi-split (196 blocks) + layer-0 xform (782 blocks)
    k_combo<<<EB_BLOCKS + XFORM_BLOCKS, BLK, 0, stream>>>(
        esrc, edst, cnt, ebuf, node_ids, emb, Wl0, bl0, Wr0, Pb0, Pb1, H);

    // fused layer-0 aggregate (LDS CSR) + layer-1 transform
    k_fused1<<<XFORM_BLOCKS, BLK, 0, stream>>>(cnt, ebuf, Pb0, Wl1, bl1, Wr1, Pb1, H);

    // layer-1 aggregate (LDS CSR) fused with graph pooling
    k_agg2_pool<<<NB_BKT, BLK, 0, stream>>>(cnt, ebuf, Pb1, H, batch, psum);

    // output projection
    k_out<<<(N_GRAPHS + 3) / 4, BLK, 0, stream>>>(batch, psum, Wout, bout, out);
}